// Round 2
// baseline (26483.466 us; speedup 1.0000x reference)
//
#include <hip/hip_runtime.h>
#include <hip/hip_fp16.h>
#include <cstddef>
#include <cstdint>

#define S 4096
#define V 32000
#define D 512
#define G3 1536       // 3*D
#define XIN 32512     // D + V
#define NA 64         // encoder layer0 blocks (8 h-idx each)
#define NB 128        // encoder layer1 blocks (4 h-idx each)
#define NE (NA + NB)
#define ND 224        // decoder blocks
#define NV 143        // ceil(V/ND)

typedef unsigned long long ull;
typedef unsigned int u32;

struct WS {
  // ---- zeroed region (memset each launch) ----
  ull h0bc[8 * D];          // tagged ring: tag=(step+1) in hi32, f32 bits in lo32
  ull h1bc[8 * D];
  u32 cnt_e[S];
  u32 cnt_d[S];
  float acc[S][152];        // s[0..149], d at [150]
  // ---- end zeroed region ----
  __half Whh0h[G3 * D];
  __half Wih1h[G3 * D];
  __half Whh1h[G3 * D];
  __half Uh[150 * V];       // [j][v] = dWih1[j][512+v]
  __half W2h[V * 50];       // [v][k]
  __half dWhh1h[152 * 50];
  __half dWih2h[152 * 50];
  __half dWhh2h[152 * 50];
  float gi_dense[152];
  float h2_hist[S * 50];
};

__device__ __forceinline__ void poll8(const ull* base, u32 exptag, float* h) {
  for (;;) {
    bool ok = true;
#pragma unroll
    for (int k = 0; k < 8; ++k) {
      ull x = __hip_atomic_load(base + k, __ATOMIC_RELAXED, __HIP_MEMORY_SCOPE_AGENT);
      ok &= ((u32)(x >> 32) == exptag);
      h[k] = __uint_as_float((u32)(x & 0xffffffffull));
    }
    if (ok) return;
    __builtin_amdgcn_s_sleep(1);
  }
}

// ---------------- setup: fp16 weight conversion ----------------
__global__ void k_convert(const float* __restrict__ eWhh0, const float* __restrict__ eWih1,
                          const float* __restrict__ eWhh1, const float* __restrict__ dWih1,
                          const float* __restrict__ dWhh1, const float* __restrict__ dWih2,
                          const float* __restrict__ dWhh2, const float* __restrict__ W2, WS* ws) {
  const int id = blockIdx.x * 256 + threadIdx.x;
  const int np = gridDim.x * 256;
  for (int e = id; e < G3 * D; e += np) {
    ws->Whh0h[e] = __float2half_rn(eWhh0[e]);
    ws->Wih1h[e] = __float2half_rn(eWih1[e]);
    ws->Whh1h[e] = __float2half_rn(eWhh1[e]);
  }
  for (int e = id; e < 150 * V; e += np) {
    int j = e / V, v = e - j * V;
    ws->Uh[e] = __float2half_rn(dWih1[(size_t)j * XIN + 512 + v]);
  }
  for (int e = id; e < V * 50; e += np) ws->W2h[e] = __float2half_rn(W2[e]);
  for (int e = id; e < 150 * 50; e += np) {
    ws->dWhh1h[e] = __float2half_rn(dWhh1[e]);
    ws->dWih2h[e] = __float2half_rn(dWih2[e]);
    ws->dWhh2h[e] = __float2half_rn(dWhh2[e]);
  }
}

// ---------------- encoder: persistent, tagged-atomic transport ----------------
__global__ __launch_bounds__(256, 1) void k_encoder(
    const int* __restrict__ input_mol, const float* __restrict__ emb,
    const float* __restrict__ eWih0, const float* __restrict__ ebih0,
    const float* __restrict__ ebhh0, const float* __restrict__ ebih1,
    const float* __restrict__ ebhh1, WS* ws) {
  __shared__ __half wlds[24 * 512];
  __shared__ float dots[24];
  __shared__ float biasHH[24];
  __shared__ float biasIH[12];
  const int tid = threadIdx.x, bid = blockIdx.x;
  const int wv = tid >> 6, ln = tid & 63;
  const bool isA = bid < NA;

  float wx[30], bihA[3];
  float hprev = 0.f;

  if (isA) {
    const int i0 = bid * 8;
    for (int e = tid; e < 24 * 512; e += 256) {
      int r = e >> 9, c = e & 511, g = r >> 3, ii = r & 7;
      wlds[e] = ws->Whh0h[(g * 512 + i0 + ii) * 512 + c];
    }
    if (tid < 24) { int g = tid >> 3, ii = tid & 7; biasHH[tid] = ebhh0[g * 512 + i0 + ii]; }
    if (tid < 8) {
      int i = i0 + tid;
#pragma unroll
      for (int g = 0; g < 3; ++g) {
        bihA[g] = ebih0[g * 512 + i];
#pragma unroll
        for (int k = 0; k < 10; ++k) wx[g * 10 + k] = eWih0[(g * 512 + i) * 10 + k];
      }
    }
  } else {
    const int i0 = (bid - NA) * 4;
    for (int e = tid; e < 12 * 512; e += 256) {
      int r = e >> 9, c = e & 511, g = r >> 2, ii = r & 3;
      wlds[e] = ws->Whh1h[(g * 512 + i0 + ii) * 512 + c];
    }
    for (int e = tid; e < 12 * 512; e += 256) {
      int r = e >> 9, c = e & 511, g = r >> 2, ii = r & 3;
      wlds[12 * 512 + e] = ws->Wih1h[(g * 512 + i0 + ii) * 512 + c];
    }
    if (tid < 12) {
      int g = tid >> 2, ii = tid & 3;
      biasHH[tid] = ebhh1[g * 512 + i0 + ii];
      biasIH[tid] = ebih1[g * 512 + i0 + ii];
    }
  }
  __syncthreads();

  for (int t = 0; t < S; ++t) {
    if (t >= 7 && tid == 0) {  // deferred ring-reuse barrier (7 steps stale -> usually satisfied)
      while (__hip_atomic_load(&ws->cnt_e[t - 7], __ATOMIC_RELAXED, __HIP_MEMORY_SCOPE_AGENT) < (u32)NE)
        __builtin_amdgcn_s_sleep(1);
    }
    if (isA) {
      // gi = Wih0 @ emb[tok] + bih0 (issue early; latency hidden under dots)
      float gr = 0.f, gz = 0.f, gn = 0.f;
      if (tid < 8) {
        int tok = input_mol[t];
        const float* x = emb + tok * 10;
        gr = bihA[0]; gz = bihA[1]; gn = bihA[2];
#pragma unroll
        for (int k = 0; k < 10; ++k) {
          float xv = x[k];
          gr += wx[k] * xv; gz += wx[10 + k] * xv; gn += wx[20 + k] * xv;
        }
      }
      float h[8];
      poll8(&ws->h0bc[(t & 7) * D + ln * 8], (u32)t, h);
#pragma unroll
      for (int rr = 0; rr < 6; ++rr) {
        int r = wv * 6 + rr;
        const __half* wrow = &wlds[r * 512 + ln * 8];
        float s = 0.f;
#pragma unroll
        for (int k = 0; k < 8; ++k) s += __half2float(wrow[k]) * h[k];
#pragma unroll
        for (int m = 32; m >= 1; m >>= 1) s += __shfl_xor(s, m, 64);
        if (ln == rr) dots[r] = s;
      }
      __syncthreads();
      if (tid < 8) {
        const int i = bid * 8 + tid;
        float hr = dots[tid] + biasHH[tid];
        float hz = dots[8 + tid] + biasHH[8 + tid];
        float hn = dots[16 + tid] + biasHH[16 + tid];
        float r = 1.f / (1.f + expf(-(gr + hr)));
        float z = 1.f / (1.f + expf(-(gz + hz)));
        float n = tanhf(gn + r * hn);
        float hN = (1.f - z) * n + z * hprev;
        hprev = hN;
        ull pk = ((ull)(u32)(t + 1) << 32) | (ull)__float_as_uint(hN);
        __hip_atomic_store(&ws->h0bc[((t + 1) & 7) * D + i], pk, __ATOMIC_RELAXED, __HIP_MEMORY_SCOPE_AGENT);
      }
    } else {
      float h1v[8];
      poll8(&ws->h1bc[(t & 7) * D + ln * 8], (u32)t, h1v);
#pragma unroll
      for (int rr = 0; rr < 3; ++rr) {
        int r = wv * 3 + rr;
        const __half* wrow = &wlds[r * 512 + ln * 8];
        float s = 0.f;
#pragma unroll
        for (int k = 0; k < 8; ++k) s += __half2float(wrow[k]) * h1v[k];
#pragma unroll
        for (int m = 32; m >= 1; m >>= 1) s += __shfl_xor(s, m, 64);
        if (ln == rr) dots[r] = s;
      }
      float h0v[8];
      poll8(&ws->h0bc[((t + 1) & 7) * D + ln * 8], (u32)(t + 1), h0v);
#pragma unroll
      for (int rr = 0; rr < 3; ++rr) {
        int r = wv * 3 + rr;
        const __half* wrow = &wlds[12 * 512 + r * 512 + ln * 8];
        float s = 0.f;
#pragma unroll
        for (int k = 0; k < 8; ++k) s += __half2float(wrow[k]) * h0v[k];
#pragma unroll
        for (int m = 32; m >= 1; m >>= 1) s += __shfl_xor(s, m, 64);
        if (ln == rr) dots[12 + r] = s;
      }
      __syncthreads();
      if (tid < 4) {
        const int i = (bid - NA) * 4 + tid;
        float hr = dots[tid] + biasHH[tid];
        float hz = dots[4 + tid] + biasHH[4 + tid];
        float hn = dots[8 + tid] + biasHH[8 + tid];
        float ir = dots[12 + tid] + biasIH[tid];
        float iz = dots[16 + tid] + biasIH[4 + tid];
        float in_ = dots[20 + tid] + biasIH[8 + tid];
        float r = 1.f / (1.f + expf(-(ir + hr)));
        float z = 1.f / (1.f + expf(-(iz + hz)));
        float n = tanhf(in_ + r * hn);
        float hN = (1.f - z) * n + z * hprev;
        hprev = hN;
        ull pk = ((ull)(u32)(t + 1) << 32) | (ull)__float_as_uint(hN);
        __hip_atomic_store(&ws->h1bc[((t + 1) & 7) * D + i], pk, __ATOMIC_RELAXED, __HIP_MEMORY_SCOPE_AGENT);
      }
    }
    __syncthreads();
    if (tid == 0)
      __hip_atomic_fetch_add(&ws->cnt_e[t], 1u, __ATOMIC_RELAXED, __HIP_MEMORY_SCOPE_AGENT);
  }
}

// ---------------- gi_dense = dWih1[:, :512] @ dense + dbih1 ----------------
__global__ void k_gidense(const float* __restrict__ dWih1, const float* __restrict__ dbih1, WS* ws) {
  __shared__ float dl[D];
  const int tid = threadIdx.x;
  // dense = h1 at t=4095 -> tag 4096 -> ring slot 0
  for (int i = tid; i < D; i += 256)
    dl[i] = __uint_as_float((u32)(ws->h1bc[i] & 0xffffffffull));
  __syncthreads();
  if (tid < 150) {
    float s = dbih1[tid];
    const float4* row = (const float4*)(dWih1 + (size_t)tid * XIN);
    for (int k = 0; k < 128; ++k) {
      float4 w = row[k];
      s += w.x * dl[4 * k] + w.y * dl[4 * k + 1] + w.z * dl[4 * k + 2] + w.w * dl[4 * k + 3];
    }
    ws->gi_dense[tid] = s;
  }
}

// ---------------- decoder: persistent, redundant GRU, convergence exit ----------------
__global__ __launch_bounds__(256, 1) void k_decoder(
    const float* __restrict__ b2, const float* __restrict__ dbhh1,
    const float* __restrict__ dbih2, const float* __restrict__ dbhh2, WS* ws) {
  __shared__ __half UL[NV][154];
  __shared__ __half W2L[NV][54];
  __shared__ float eL[NV];
  __shared__ float b2L[NV];
  __shared__ float giL[150];
  __shared__ float ghL[150];
  __shared__ float h1L[52];
  __shared__ float h2L[52];
  __shared__ float convd[52];
  __shared__ float red[4];
  __shared__ float sdinv;
  __shared__ int convS;

  const int tid = threadIdx.x, bid = blockIdx.x;
  const int wv = tid >> 6, ln = tid & 63;
  const int v0 = bid * NV;
  const int nv = (V - v0 < NV) ? (V - v0) : NV;

  for (int j = 0; j < 150; ++j)
    for (int v = tid; v < nv; v += 256) UL[v][j] = ws->Uh[(size_t)j * V + v0 + v];
  for (int v = tid; v < nv; v += 256) {
    for (int k = 0; k < 50; ++k) W2L[v][k] = ws->W2h[(v0 + v) * 50 + k];
    b2L[v] = b2[v0 + v];
  }
  __half2 wh1r[25], wi2r[25], wh2r[25];
  float bh1 = 0.f, bi2 = 0.f, bh2 = 0.f;
  if (tid < 150) {
    const __half2* p1 = (const __half2*)&ws->dWhh1h[tid * 50];
    const __half2* p2 = (const __half2*)&ws->dWih2h[tid * 50];
    const __half2* p3 = (const __half2*)&ws->dWhh2h[tid * 50];
#pragma unroll
    for (int m = 0; m < 25; ++m) { wh1r[m] = p1[m]; wi2r[m] = p2[m]; wh2r[m] = p3[m]; }
    bh1 = dbhh1[tid]; bi2 = dbih2[tid]; bh2 = dbhh2[tid];
  }
  if (tid < 50) { h1L[tid] = 0.f; h2L[tid] = 0.f; }
  float hp1 = 0.f, hp2 = 0.f, d1 = 0.f, d2 = 0.f;
  __syncthreads();

  for (int t = 0; t < S; ++t) {
    // (a) gi1 = gi_dense + s/d from acc[t-1] (fb feedback); fb_{-1}=0
    if (t > 0) {
      if (tid == 0)
        sdinv = 1.f / __hip_atomic_load(&ws->acc[t - 1][150], __ATOMIC_RELAXED, __HIP_MEMORY_SCOPE_AGENT);
      __syncthreads();
      if (tid < 150)
        giL[tid] = ws->gi_dense[tid] +
                   __hip_atomic_load(&ws->acc[t - 1][tid], __ATOMIC_RELAXED, __HIP_MEMORY_SCOPE_AGENT) * sdinv;
    } else {
      if (tid < 150) giL[tid] = ws->gi_dense[tid];
    }
    // (b) layer1
    if (tid < 150) {
      float s = bh1;
#pragma unroll
      for (int m = 0; m < 25; ++m) {
        float2 w = __half22float2(wh1r[m]);
        s += w.x * h1L[2 * m] + w.y * h1L[2 * m + 1];
      }
      ghL[tid] = s;
    }
    __syncthreads();
    if (tid < 50) {
      float r = 1.f / (1.f + expf(-(giL[tid] + ghL[tid])));
      float z = 1.f / (1.f + expf(-(giL[50 + tid] + ghL[50 + tid])));
      float n = tanhf(giL[100 + tid] + r * ghL[100 + tid]);
      float hN = (1.f - z) * n + z * hp1;
      d1 = fabsf(hN - hp1);
      hp1 = hN;
      h1L[tid] = hN;
    }
    __syncthreads();
    // (c) layer2
    if (tid < 150) {
      float s1 = bi2, s2 = bh2;
#pragma unroll
      for (int m = 0; m < 25; ++m) {
        float2 wa = __half22float2(wi2r[m]);
        float2 wb = __half22float2(wh2r[m]);
        s1 += wa.x * h1L[2 * m] + wa.y * h1L[2 * m + 1];
        s2 += wb.x * h2L[2 * m] + wb.y * h2L[2 * m + 1];
      }
      giL[tid] = s1; ghL[tid] = s2;
    }
    __syncthreads();
    if (tid < 50) {
      float r = 1.f / (1.f + expf(-(giL[tid] + ghL[tid])));
      float z = 1.f / (1.f + expf(-(giL[50 + tid] + ghL[50 + tid])));
      float n = tanhf(giL[100 + tid] + r * ghL[100 + tid]);
      float hN = (1.f - z) * n + z * hp2;
      d2 = fabsf(hN - hp2);
      hp2 = hN;
      h2L[tid] = hN;
      if (bid == 0) ws->h2_hist[t * 50 + tid] = hN;
      convd[tid] = fmaxf(d1, d2);
    }
    __syncthreads();
    // (d) slice logits + exp
    for (int v = tid; v < nv; v += 256) {
      float l = b2L[v];
      const __half2* wp = (const __half2*)&W2L[v][0];
#pragma unroll
      for (int k = 0; k < 25; ++k) {
        float2 w = __half22float2(wp[k]);
        l += w.x * h2L[2 * k] + w.y * h2L[2 * k + 1];
      }
      eL[v] = expf(l);
    }
    __syncthreads();
    float dp = 0.f;
    for (int v = tid; v < nv; v += 256) dp += eL[v];
#pragma unroll
    for (int m = 32; m >= 1; m >>= 1) dp += __shfl_xor(dp, m, 64);
    if (ln == 0) red[wv] = dp;
    float sj = 0.f;
    if (tid < 150) {
      for (int v = 0; v < nv; ++v) sj += eL[v] * __half2float(UL[v][tid]);
    }
    __syncthreads();
    if (tid < 150) unsafeAtomicAdd(&ws->acc[t][tid], sj);
    if (tid == 160) unsafeAtomicAdd(&ws->acc[t][150], red[0] + red[1] + red[2] + red[3]);
    __syncthreads();  // drains vmcnt -> all this block's atomics complete
    if (tid == 0) {
      __hip_atomic_fetch_add(&ws->cnt_d[t], 1u, __ATOMIC_RELEASE, __HIP_MEMORY_SCOPE_AGENT);
      u32 c;
      do {
        c = __hip_atomic_load(&ws->cnt_d[t], __ATOMIC_RELAXED, __HIP_MEMORY_SCOPE_AGENT);
        if (c < (u32)ND) __builtin_amdgcn_s_sleep(2);
      } while (c < (u32)ND);
      __builtin_amdgcn_fence(__ATOMIC_ACQUIRE, "agent");
      float mx = 0.f;
      for (int i2 = 0; i2 < 50; ++i2) mx = fmaxf(mx, convd[i2]);
      convS = (t >= 3 && mx < 2e-6f) ? 1 : 0;
    }
    __syncthreads();
    if (convS) {  // fixed point reached: fill tail and exit (identical decision in all blocks)
      float dfin = __hip_atomic_load(&ws->acc[t][150], __ATOMIC_RELAXED, __HIP_MEMORY_SCOPE_AGENT);
      for (int tp = t + 1 + bid; tp < S; tp += ND) {
        if (tid < 50) ws->h2_hist[tp * 50 + tid] = h2L[tid];
        if (tid == 64) ws->acc[tp][150] = dfin;
      }
      break;
    }
  }
}

// ---------------- epilogue: probs = exp(W2 h2 + b2) / d ----------------
__global__ __launch_bounds__(256, 1) void k_final(const float* __restrict__ b2, WS* ws,
                                                  float* __restrict__ out) {
  __shared__ __half W2L[500 * 50];
  __shared__ float h2T[16 * 50];
  __shared__ float invd[16];
  __shared__ float b2L[500];
  const int tid = threadIdx.x;
  const int bt = blockIdx.x >> 6;
  const int bv = blockIdx.x & 63;
  const int t0 = bt * 16, v0 = bv * 500;

  for (int v = tid; v < 500; v += 256) {
    const __half* src = &ws->W2h[(v0 + v) * 50];
#pragma unroll
    for (int k = 0; k < 50; ++k) W2L[v * 50 + k] = src[k];
    b2L[v] = b2[v0 + v];
  }
  for (int e = tid; e < 16 * 50; e += 256) h2T[e] = ws->h2_hist[t0 * 50 + e];
  if (tid < 16) invd[tid] = 1.f / ws->acc[t0 + tid][150];
  __syncthreads();

  for (int tt = 0; tt < 16; ++tt) {
    const float* h2 = &h2T[tt * 50];
    float iv = invd[tt];
    for (int v = tid; v < 500; v += 256) {
      float l = b2L[v];
      const __half2* wp = (const __half2*)&W2L[v * 50];
#pragma unroll
      for (int k = 0; k < 25; ++k) {
        float2 w = __half22float2(wp[k]);
        l += w.x * h2[2 * k] + w.y * h2[2 * k + 1];
      }
      out[(size_t)(t0 + tt) * V + v0 + v] = expf(l) * iv;
    }
  }
}

extern "C" void kernel_launch(void* const* d_in, const int* in_sizes, int n_in,
                              void* d_out, int out_size, void* d_ws, size_t ws_size,
                              hipStream_t stream) {
  const int* input_mol = (const int*)d_in[0];
  const float* emb = (const float*)d_in[1];
  const float* eWih0 = (const float*)d_in[2];
  const float* eWhh0 = (const float*)d_in[3];
  const float* ebih0 = (const float*)d_in[4];
  const float* ebhh0 = (const float*)d_in[5];
  const float* eWih1 = (const float*)d_in[6];
  const float* eWhh1 = (const float*)d_in[7];
  const float* ebih1 = (const float*)d_in[8];
  const float* ebhh1 = (const float*)d_in[9];
  const float* dWih1 = (const float*)d_in[10];
  const float* dWhh1 = (const float*)d_in[11];
  const float* dbih1 = (const float*)d_in[12];
  const float* dbhh1 = (const float*)d_in[13];
  const float* dWih2 = (const float*)d_in[14];
  const float* dWhh2 = (const float*)d_in[15];
  const float* dbih2 = (const float*)d_in[16];
  const float* dbhh2 = (const float*)d_in[17];
  const float* W2 = (const float*)d_in[18];
  const float* b2 = (const float*)d_in[19];
  float* out = (float*)d_out;
  WS* ws = (WS*)d_ws;
  if (ws_size < sizeof(WS)) return;  // workspace too small -> will show as failure

  const size_t zero_bytes = offsetof(WS, Whh0h);
  (void)hipMemsetAsync(d_ws, 0, zero_bytes, stream);
  k_convert<<<2048, 256, 0, stream>>>(eWhh0, eWih1, eWhh1, dWih1, dWhh1, dWih2, dWhh2, W2, ws);
  k_encoder<<<NE, 256, 0, stream>>>(input_mol, emb, eWih0, ebih0, ebhh0, ebih1, ebhh1, ws);
  k_gidense<<<1, 256, 0, stream>>>(dWih1, dbih1, ws);
  k_decoder<<<ND, 256, 0, stream>>>(b2, dbhh1, dbih2, dbhh2, ws);
  k_final<<<16384, 256, 0, stream>>>(b2, ws, out);
}